// Round 6
// baseline (704.461 us; speedup 1.0000x reference)
//
#include <hip/hip_runtime.h>
#include <hip/hip_bf16.h>
#include <math.h>

#define N_NODES 40000
#define NE      640000
#define FIN     33
#define H       128
#define COUT    3
#define NLAYERS 8
#define ALPHA   0.1f
#define THETA   0.5f
#define SCAN_B  157            // ceil(N_NODES / 256)

typedef __bf16 bf16x8 __attribute__((ext_vector_type(8)));
typedef float  f32x4  __attribute__((ext_vector_type(4)));

__device__ inline unsigned short f2bf(float f) {
    __hip_bfloat16 b = __float2bfloat16(f);
    return *(unsigned short*)&b;
}
__device__ inline float bf2f(unsigned short u) {
    __hip_bfloat16 b = *(__hip_bfloat16*)&u;
    return __bfloat162float(b);
}

// ---------------- CSR build ----------------
__global__ void k_hist(const int* __restrict__ row, int* __restrict__ counts) {
    int e = blockIdx.x * blockDim.x + threadIdx.x;
    if (e < NE) atomicAdd(&counts[row[e]], 1);
}

__global__ __launch_bounds__(256) void k_scan1(const int* __restrict__ counts,
                        int* __restrict__ row_ptr, int* __restrict__ partial) {
    __shared__ int s[256];
    int t = threadIdx.x, i = blockIdx.x * 256 + t;
    int v = (i < N_NODES) ? counts[i] : 0;
    s[t] = v;
    __syncthreads();
    for (int off = 1; off < 256; off <<= 1) {
        int x = s[t];
        int add = (t >= off) ? s[t - off] : 0;
        __syncthreads();
        s[t] = x + add;
        __syncthreads();
    }
    if (i < N_NODES) row_ptr[i] = s[t] - v;      // exclusive within block
    if (t == 255) partial[blockIdx.x] = s[255];
}

__global__ __launch_bounds__(256) void k_scan2(int* __restrict__ partial) {
    __shared__ int s[256];
    int t = threadIdx.x;
    int v = (t < SCAN_B) ? partial[t] : 0;
    s[t] = v;
    __syncthreads();
    for (int off = 1; off < 256; off <<= 1) {
        int x = s[t];
        int add = (t >= off) ? s[t - off] : 0;
        __syncthreads();
        s[t] = x + add;
        __syncthreads();
    }
    if (t < SCAN_B) partial[t] = s[t] - v;       // exclusive base
}

__global__ __launch_bounds__(256) void k_scan3(const int* __restrict__ partial,
                        int* __restrict__ row_ptr, int* __restrict__ cursor) {
    int t = threadIdx.x, i = blockIdx.x * 256 + t;
    if (i < N_NODES) {
        int v = row_ptr[i] + partial[blockIdx.x];
        row_ptr[i] = v;
        cursor[i] = v;
    }
    if (i == 0) row_ptr[N_NODES] = NE;
}

// pack edge -> 4 bytes: [bf16 weight | 16-bit col]   (N=40000 < 65536)
__global__ void k_scatter(const int* __restrict__ row, const int* __restrict__ col,
                          const float* __restrict__ w, int* __restrict__ cursor,
                          unsigned int* __restrict__ ep4) {
    int e = blockIdx.x * blockDim.x + threadIdx.x;
    if (e < NE) {
        int r = row[e];
        int pos = atomicAdd(&cursor[r], 1);
        unsigned int wb = f2bf((1.0f - ALPHA) * w[e]);
        ep4[pos] = (wb << 16) | (unsigned int)col[e];
    }
}

// ---- Wtbf[l][j][k] = bf16(W[l][k][j])  (B operand for MFMA, row = output col)
__global__ __launch_bounds__(256) void k_wprep(const float* __restrict__ W,
                        unsigned short* __restrict__ Wtbf) {
    int idx = blockIdx.x * 256 + threadIdx.x;     // 8*128*128 = 131072
    int l = idx >> 14;
    int rem = idx & 16383;
    int k = rem >> 7, j = rem & 127;
    Wtbf[l * 16384 + j * 128 + k] = f2bf(W[idx]); // W[idx] = W[l][k][j], coalesced read
}

// ---- x0 = relu(x @ W_in^T + b_in); h = x0 (fp32); halves in bf16 ----------
__global__ __launch_bounds__(256) void k_xin(const float* __restrict__ x,
                      const float* __restrict__ Win, const float* __restrict__ bin,
                      float* __restrict__ h,
                      unsigned short* __restrict__ x0bf0, unsigned short* __restrict__ x0bf1,
                      unsigned short* __restrict__ hbf0,  unsigned short* __restrict__ hbf1) {
    __shared__ float sW[H * FIN];      // 16.9 KB
    __shared__ float sx[16][FIN];      // 2.1 KB
    int t = threadIdx.x;
    for (int i = t; i < H * FIN; i += 256) sW[i] = Win[i];
    int n0 = blockIdx.x * 16;
    for (int i = t; i < 16 * FIN; i += 256)
        sx[i / FIN][i % FIN] = x[(size_t)(n0 + i / FIN) * FIN + (i % FIN)];
    __syncthreads();
    int f = t % H;
    int l0 = t / H;                    // 0..1
    float bv = bin[f];
    unsigned short* x0h = (f < 64) ? x0bf0 : x0bf1;
    unsigned short* hh  = (f < 64) ? hbf0  : hbf1;
    int c = f & 63;
    for (int lo = l0; lo < 16; lo += 2) {
        float acc = bv;
        #pragma unroll
        for (int k = 0; k < FIN; k++) acc += sx[lo][k] * sW[f * FIN + k];
        acc = fmaxf(acc, 0.f);
        int n = n0 + lo;
        h[(size_t)n * H + f] = acc;
        unsigned short b = f2bf(acc);
        x0h[(size_t)n * 64 + c] = b;
        hh [(size_t)n * 64 + c] = b;
    }
}

// ---- half-column SpMM: xx[:, colbase:colbase+64] from compact [N,64] half --
// wave per row, lane = one column; 8 independent chains (deg~16 -> 2 iters)
__global__ __launch_bounds__(256) void k_spmm_half(const int* __restrict__ row_ptr,
                       const unsigned int* __restrict__ ep4,
                       const unsigned short* __restrict__ hh,    // [N][64] bf16
                       const unsigned short* __restrict__ x0h,   // [N][64] bf16
                       unsigned short* __restrict__ xxbf, int colbase) {
    int wave = (blockIdx.x * blockDim.x + threadIdx.x) >> 6;
    int lane = threadIdx.x & 63;
    if (wave >= N_NODES) return;
    int beg = row_ptr[wave], end = row_ptr[wave + 1];
    float a0 = 0.f, a1 = 0.f, a2 = 0.f, a3 = 0.f;
    float a4 = 0.f, a5 = 0.f, a6 = 0.f, a7 = 0.f;
    int e = beg;
    for (; e + 8 <= end; e += 8) {
        unsigned int u0 = ep4[e],     u1 = ep4[e + 1], u2 = ep4[e + 2], u3 = ep4[e + 3];
        unsigned int u4 = ep4[e + 4], u5 = ep4[e + 5], u6 = ep4[e + 6], u7 = ep4[e + 7];
        unsigned short v0 = hh[(size_t)(u0 & 0xffffu) * 64 + lane];
        unsigned short v1 = hh[(size_t)(u1 & 0xffffu) * 64 + lane];
        unsigned short v2 = hh[(size_t)(u2 & 0xffffu) * 64 + lane];
        unsigned short v3 = hh[(size_t)(u3 & 0xffffu) * 64 + lane];
        unsigned short v4 = hh[(size_t)(u4 & 0xffffu) * 64 + lane];
        unsigned short v5 = hh[(size_t)(u5 & 0xffffu) * 64 + lane];
        unsigned short v6 = hh[(size_t)(u6 & 0xffffu) * 64 + lane];
        unsigned short v7 = hh[(size_t)(u7 & 0xffffu) * 64 + lane];
        a0 += bf2f(u0 >> 16) * bf2f(v0);
        a1 += bf2f(u1 >> 16) * bf2f(v1);
        a2 += bf2f(u2 >> 16) * bf2f(v2);
        a3 += bf2f(u3 >> 16) * bf2f(v3);
        a4 += bf2f(u4 >> 16) * bf2f(v4);
        a5 += bf2f(u5 >> 16) * bf2f(v5);
        a6 += bf2f(u6 >> 16) * bf2f(v6);
        a7 += bf2f(u7 >> 16) * bf2f(v7);
    }
    for (; e + 2 <= end; e += 2) {
        unsigned int u0 = ep4[e], u1 = ep4[e + 1];
        unsigned short v0 = hh[(size_t)(u0 & 0xffffu) * 64 + lane];
        unsigned short v1 = hh[(size_t)(u1 & 0xffffu) * 64 + lane];
        a0 += bf2f(u0 >> 16) * bf2f(v0);
        a1 += bf2f(u1 >> 16) * bf2f(v1);
    }
    if (e < end) {
        unsigned int u = ep4[e];
        a2 += bf2f(u >> 16) * bf2f(hh[(size_t)(u & 0xffffu) * 64 + lane]);
    }
    float o = ((a0 + a1) + (a2 + a3)) + ((a4 + a5) + (a6 + a7))
            + ALPHA * bf2f(x0h[(size_t)wave * 64 + lane]);
    xxbf[(size_t)wave * H + colbase + lane] = f2bf(o);
}

// ---- MFMA GEMM + epilogue: h += relu((1-b)*xx + b*(xx@W)); hbf halves -----
// block = 4 waves, 64 rows; wave = 16 rows x 128 cols (8 16x16 acc tiles).
__global__ __launch_bounds__(256) void k_gemm(const unsigned short* __restrict__ xxbf,
                       float* __restrict__ h, const unsigned short* __restrict__ Wtbf,
                       unsigned short* __restrict__ hbf0, unsigned short* __restrict__ hbf1,
                       float beta) {
    int t = threadIdx.x;
    int wv = t >> 6, lane = t & 63;
    int quad = lane >> 4, l16 = lane & 15;
    int rbase = blockIdx.x * 64 + wv * 16;

    f32x4 acc[8];
    #pragma unroll
    for (int j = 0; j < 8; j++) acc[j] = (f32x4){0.f, 0.f, 0.f, 0.f};

    #pragma unroll
    for (int k0 = 0; k0 < 4; k0++) {
        bf16x8 av = *(const bf16x8*)(xxbf + (size_t)(rbase + l16) * H + k0 * 32 + quad * 8);
        #pragma unroll
        for (int j = 0; j < 8; j++) {
            bf16x8 bv = *(const bf16x8*)(Wtbf + (size_t)(j * 16 + l16) * H + k0 * 32 + quad * 8);
            acc[j] = __builtin_amdgcn_mfma_f32_16x16x32_bf16(av, bv, acc[j], 0, 0, 0);
        }
    }

    float omb = 1.f - beta;
    #pragma unroll
    for (int j = 0; j < 8; j++) {
        int col = j * 16 + l16;
        unsigned short* hh = (col < 64) ? hbf0 : hbf1;
        int c = col & 63;
        #pragma unroll
        for (int r = 0; r < 4; r++) {
            int row = rbase + quad * 4 + r;        // C/D: row = quad*4 + reg
            size_t idx = (size_t)row * H + col;
            float sk = bf2f(xxbf[idx]);            // skip term (bf16)
            float o = omb * sk + beta * acc[j][r];
            float hv = h[idx] + fmaxf(o, 0.f);
            h[idx] = hv;
            hh[(size_t)row * 64 + c] = f2bf(hv);
        }
    }
}

// ---------------- out = h @ W_out^T + b_out  (wave per node) ----------------
__global__ __launch_bounds__(256) void k_out(const float* __restrict__ h,
                      const float* __restrict__ Wout, const float* __restrict__ bout,
                      float* __restrict__ out) {
    int wave = (blockIdx.x * blockDim.x + threadIdx.x) >> 6;
    int lane = threadIdx.x & 63;
    if (wave >= N_NODES) return;
    float2 v = ((const float2*)(h + (size_t)wave * H))[lane];
    float p0, p1, p2;
    {
        float2 w0 = ((const float2*)(Wout + 0 * H))[lane];
        float2 w1 = ((const float2*)(Wout + 1 * H))[lane];
        float2 w2 = ((const float2*)(Wout + 2 * H))[lane];
        p0 = v.x * w0.x + v.y * w0.y;
        p1 = v.x * w1.x + v.y * w1.y;
        p2 = v.x * w2.x + v.y * w2.y;
    }
    #pragma unroll
    for (int off = 32; off > 0; off >>= 1) {
        p0 += __shfl_down(p0, off);
        p1 += __shfl_down(p1, off);
        p2 += __shfl_down(p2, off);
    }
    if (lane == 0) {
        out[(size_t)wave * 3 + 0] = p0 + bout[0];
        out[(size_t)wave * 3 + 1] = p1 + bout[1];
        out[(size_t)wave * 3 + 2] = p2 + bout[2];
    }
}

extern "C" void kernel_launch(void* const* d_in, const int* in_sizes, int n_in,
                              void* d_out, int out_size, void* d_ws, size_t ws_size,
                              hipStream_t stream) {
    const float* x     = (const float*)d_in[0];
    const int*   erow  = (const int*)  d_in[1];
    const int*   ecol  = (const int*)  d_in[2];
    const float* ew    = (const float*)d_in[3];
    const float* Win   = (const float*)d_in[4];
    const float* bin   = (const float*)d_in[5];
    const float* Wout  = (const float*)d_in[6];
    const float* bout  = (const float*)d_in[7];
    const float* Wconv = (const float*)d_in[8];
    float* out = (float*)d_out;

    char* ws = (char*)d_ws;
    const size_t NHf = (size_t)N_NODES * H * sizeof(float);           // 20,480,000
    const size_t NHb = (size_t)N_NODES * H * sizeof(unsigned short);  // 10,240,000
    const size_t NHh = NHb / 2;                                       //  5,120,000
    float*          h     = (float*)(ws);
    unsigned short* xxbf  = (unsigned short*)(ws + NHf);
    unsigned short* x0bf0 = (unsigned short*)(ws + NHf + NHb);
    unsigned short* x0bf1 = (unsigned short*)(ws + NHf + NHb + NHh);
    unsigned short* hbf0  = (unsigned short*)(ws + NHf + 2 * NHb);
    unsigned short* hbf1  = (unsigned short*)(ws + NHf + 2 * NHb + NHh);
    char* p = ws + NHf + 3 * NHb;
    unsigned short* Wtbf  = (unsigned short*)p;  p += 8 * H * H * 2;  // 262,144
    int*  counts  = (int*) p;  p += 160256;
    int*  row_ptr = (int*) p;  p += 160256;
    int*  cursor  = (int*) p;  p += 160256;
    int*  partial = (int*) p;  p += 1024;
    unsigned int* ep4 = (unsigned int*)p;        // NE * 4 bytes

    // CSR build (inputs restored pristine before every call)
    hipMemsetAsync(counts, 0, (size_t)N_NODES * 4, stream);
    k_hist   <<<NE / 256, 256, 0, stream>>>(erow, counts);
    k_scan1  <<<SCAN_B,   256, 0, stream>>>(counts, row_ptr, partial);
    k_scan2  <<<1,        256, 0, stream>>>(partial);
    k_scan3  <<<SCAN_B,   256, 0, stream>>>(partial, row_ptr, cursor);
    k_scatter<<<NE / 256, 256, 0, stream>>>(erow, ecol, ew, cursor, ep4);

    // weight prep + input projection
    k_wprep<<<8 * H * H / 256, 256, 0, stream>>>(Wconv, Wtbf);
    k_xin  <<<N_NODES / 16,    256, 0, stream>>>(x, Win, bin, h, x0bf0, x0bf1, hbf0, hbf1);

    // layers: two L2-resident half-column spmm passes, then MFMA gemm
    for (int l = 0; l < NLAYERS; l++) {
        float beta = logf(THETA / (float)(l + 1) + 1.0f);
        k_spmm_half<<<N_NODES / 4, 256, 0, stream>>>(row_ptr, ep4, hbf0, x0bf0, xxbf, 0);
        k_spmm_half<<<N_NODES / 4, 256, 0, stream>>>(row_ptr, ep4, hbf1, x0bf1, xxbf, 64);
        k_gemm<<<N_NODES / 64, 256, 0, stream>>>(xxbf, h, Wtbf + (size_t)l * H * H,
                                                 hbf0, hbf1, beta);
    }

    // output projection
    k_out<<<N_NODES / 4, 256, 0, stream>>>(h, Wout, bout, out);
}

// Round 7
// 557.302 us; speedup vs baseline: 1.2641x; 1.2641x over previous
//
#include <hip/hip_runtime.h>
#include <hip/hip_bf16.h>
#include <math.h>

#define N_NODES 40000
#define NE      640000
#define FIN     33
#define H       128
#define COUT    3
#define NLAYERS 8
#define ALPHA   0.1f
#define THETA   0.5f
#define SCAN_B  157            // ceil(N_NODES / 256)

typedef __bf16 bf16x8 __attribute__((ext_vector_type(8)));
typedef float  f32x4  __attribute__((ext_vector_type(4)));

__device__ inline unsigned short f2bf(float f) {
    __hip_bfloat16 b = __float2bfloat16(f);
    return *(unsigned short*)&b;
}
__device__ inline float bf2f(unsigned short u) {
    __hip_bfloat16 b = *(__hip_bfloat16*)&u;
    return __bfloat162float(b);
}

// ---------------- CSR build ----------------
__global__ void k_hist(const int* __restrict__ row, int* __restrict__ counts) {
    int e = blockIdx.x * blockDim.x + threadIdx.x;
    if (e < NE) atomicAdd(&counts[row[e]], 1);
}

__global__ __launch_bounds__(256) void k_scan1(const int* __restrict__ counts,
                        int* __restrict__ row_ptr, int* __restrict__ partial) {
    __shared__ int s[256];
    int t = threadIdx.x, i = blockIdx.x * 256 + t;
    int v = (i < N_NODES) ? counts[i] : 0;
    s[t] = v;
    __syncthreads();
    for (int off = 1; off < 256; off <<= 1) {
        int x = s[t];
        int add = (t >= off) ? s[t - off] : 0;
        __syncthreads();
        s[t] = x + add;
        __syncthreads();
    }
    if (i < N_NODES) row_ptr[i] = s[t] - v;      // exclusive within block
    if (t == 255) partial[blockIdx.x] = s[255];
}

__global__ __launch_bounds__(256) void k_scan2(int* __restrict__ partial) {
    __shared__ int s[256];
    int t = threadIdx.x;
    int v = (t < SCAN_B) ? partial[t] : 0;
    s[t] = v;
    __syncthreads();
    for (int off = 1; off < 256; off <<= 1) {
        int x = s[t];
        int add = (t >= off) ? s[t - off] : 0;
        __syncthreads();
        s[t] = x + add;
        __syncthreads();
    }
    if (t < SCAN_B) partial[t] = s[t] - v;       // exclusive base
}

__global__ __launch_bounds__(256) void k_scan3(const int* __restrict__ partial,
                        int* __restrict__ row_ptr, int* __restrict__ cursor) {
    int t = threadIdx.x, i = blockIdx.x * 256 + t;
    if (i < N_NODES) {
        int v = row_ptr[i] + partial[blockIdx.x];
        row_ptr[i] = v;
        cursor[i] = v;
    }
    if (i == 0) row_ptr[N_NODES] = NE;
}

// pack edge -> 4 bytes: [bf16 weight | 16-bit col]   (N=40000 < 65536)
__global__ void k_scatter(const int* __restrict__ row, const int* __restrict__ col,
                          const float* __restrict__ w, int* __restrict__ cursor,
                          unsigned int* __restrict__ ep4) {
    int e = blockIdx.x * blockDim.x + threadIdx.x;
    if (e < NE) {
        int r = row[e];
        int pos = atomicAdd(&cursor[r], 1);
        unsigned int wb = f2bf((1.0f - ALPHA) * w[e]);
        ep4[pos] = (wb << 16) | (unsigned int)col[e];
    }
}

// ---- Wtbf[l][j][k] = bf16(W[l][k][j])  (B operand for MFMA, row = output col)
__global__ __launch_bounds__(256) void k_wprep(const float* __restrict__ W,
                        unsigned short* __restrict__ Wtbf) {
    int idx = blockIdx.x * 256 + threadIdx.x;     // 8*128*128 = 131072
    int l = idx >> 14;
    int rem = idx & 16383;
    int k = rem >> 7, j = rem & 127;
    Wtbf[l * 16384 + j * 128 + k] = f2bf(W[idx]); // W[idx] = W[l][k][j], coalesced read
}

// ---- x0 = relu(x @ W_in^T + b_in); h = x0 (fp32); x0bf, hbf = bf16(x0) ----
__global__ __launch_bounds__(256) void k_xin(const float* __restrict__ x,
                      const float* __restrict__ Win, const float* __restrict__ bin,
                      float* __restrict__ h, unsigned short* __restrict__ x0bf,
                      unsigned short* __restrict__ hbf) {
    __shared__ float sW[H * FIN];      // 16.9 KB
    __shared__ float sx[16][FIN];      // 2.1 KB
    int t = threadIdx.x;
    for (int i = t; i < H * FIN; i += 256) sW[i] = Win[i];
    int n0 = blockIdx.x * 16;
    for (int i = t; i < 16 * FIN; i += 256)
        sx[i / FIN][i % FIN] = x[(size_t)(n0 + i / FIN) * FIN + (i % FIN)];
    __syncthreads();
    int f = t % H;
    int l0 = t / H;                    // 0..1
    float bv = bin[f];
    for (int lo = l0; lo < 16; lo += 2) {
        float acc = bv;
        #pragma unroll
        for (int k = 0; k < FIN; k++) acc += sx[lo][k] * sW[f * FIN + k];
        acc = fmaxf(acc, 0.f);
        size_t idx = (size_t)(n0 + lo) * H + f;
        h[idx] = acc;
        unsigned short b = f2bf(acc);
        x0bf[idx] = b;
        hbf[idx] = b;
    }
}

// ---- xx = A@hbf + alpha*x0bf -> bf16; wave/row, full 128-col gather -------
// one 256 B gather per edge; 8 independent chains (deg~16 -> 2 main iters)
__global__ __launch_bounds__(256) void k_spmm(const int* __restrict__ row_ptr,
                       const unsigned int* __restrict__ ep4,
                       const unsigned short* __restrict__ hbf,
                       const unsigned short* __restrict__ x0bf,
                       unsigned short* __restrict__ xxbf) {
    int wave = (blockIdx.x * blockDim.x + threadIdx.x) >> 6;
    int lane = threadIdx.x & 63;
    if (wave >= N_NODES) return;
    int beg = row_ptr[wave], end = row_ptr[wave + 1];
    float ax0 = 0.f, ay0 = 0.f, ax1 = 0.f, ay1 = 0.f;
    float ax2 = 0.f, ay2 = 0.f, ax3 = 0.f, ay3 = 0.f;
    float ax4 = 0.f, ay4 = 0.f, ax5 = 0.f, ay5 = 0.f;
    float ax6 = 0.f, ay6 = 0.f, ax7 = 0.f, ay7 = 0.f;
    int e = beg;
    for (; e + 8 <= end; e += 8) {
        unsigned int u0 = ep4[e],     u1 = ep4[e + 1], u2 = ep4[e + 2], u3 = ep4[e + 3];
        unsigned int u4 = ep4[e + 4], u5 = ep4[e + 5], u6 = ep4[e + 6], u7 = ep4[e + 7];
        __hip_bfloat162 v0 = ((const __hip_bfloat162*)(hbf + (size_t)(u0 & 0xffffu) * H))[lane];
        __hip_bfloat162 v1 = ((const __hip_bfloat162*)(hbf + (size_t)(u1 & 0xffffu) * H))[lane];
        __hip_bfloat162 v2 = ((const __hip_bfloat162*)(hbf + (size_t)(u2 & 0xffffu) * H))[lane];
        __hip_bfloat162 v3 = ((const __hip_bfloat162*)(hbf + (size_t)(u3 & 0xffffu) * H))[lane];
        __hip_bfloat162 v4 = ((const __hip_bfloat162*)(hbf + (size_t)(u4 & 0xffffu) * H))[lane];
        __hip_bfloat162 v5 = ((const __hip_bfloat162*)(hbf + (size_t)(u5 & 0xffffu) * H))[lane];
        __hip_bfloat162 v6 = ((const __hip_bfloat162*)(hbf + (size_t)(u6 & 0xffffu) * H))[lane];
        __hip_bfloat162 v7 = ((const __hip_bfloat162*)(hbf + (size_t)(u7 & 0xffffu) * H))[lane];
        float w0 = bf2f(u0 >> 16), w1 = bf2f(u1 >> 16), w2 = bf2f(u2 >> 16), w3 = bf2f(u3 >> 16);
        float w4 = bf2f(u4 >> 16), w5 = bf2f(u5 >> 16), w6 = bf2f(u6 >> 16), w7 = bf2f(u7 >> 16);
        ax0 += w0 * __bfloat162float(v0.x); ay0 += w0 * __bfloat162float(v0.y);
        ax1 += w1 * __bfloat162float(v1.x); ay1 += w1 * __bfloat162float(v1.y);
        ax2 += w2 * __bfloat162float(v2.x); ay2 += w2 * __bfloat162float(v2.y);
        ax3 += w3 * __bfloat162float(v3.x); ay3 += w3 * __bfloat162float(v3.y);
        ax4 += w4 * __bfloat162float(v4.x); ay4 += w4 * __bfloat162float(v4.y);
        ax5 += w5 * __bfloat162float(v5.x); ay5 += w5 * __bfloat162float(v5.y);
        ax6 += w6 * __bfloat162float(v6.x); ay6 += w6 * __bfloat162float(v6.y);
        ax7 += w7 * __bfloat162float(v7.x); ay7 += w7 * __bfloat162float(v7.y);
    }
    for (; e + 2 <= end; e += 2) {
        unsigned int u0 = ep4[e], u1 = ep4[e + 1];
        __hip_bfloat162 v0 = ((const __hip_bfloat162*)(hbf + (size_t)(u0 & 0xffffu) * H))[lane];
        __hip_bfloat162 v1 = ((const __hip_bfloat162*)(hbf + (size_t)(u1 & 0xffffu) * H))[lane];
        float w0 = bf2f(u0 >> 16), w1 = bf2f(u1 >> 16);
        ax0 += w0 * __bfloat162float(v0.x); ay0 += w0 * __bfloat162float(v0.y);
        ax1 += w1 * __bfloat162float(v1.x); ay1 += w1 * __bfloat162float(v1.y);
    }
    if (e < end) {
        unsigned int u = ep4[e];
        __hip_bfloat162 v = ((const __hip_bfloat162*)(hbf + (size_t)(u & 0xffffu) * H))[lane];
        float w = bf2f(u >> 16);
        ax2 += w * __bfloat162float(v.x); ay2 += w * __bfloat162float(v.y);
    }
    __hip_bfloat162 xv = ((const __hip_bfloat162*)(x0bf + (size_t)wave * H))[lane];
    float ox = ((ax0 + ax1) + (ax2 + ax3)) + ((ax4 + ax5) + (ax6 + ax7))
             + ALPHA * __bfloat162float(xv.x);
    float oy = ((ay0 + ay1) + (ay2 + ay3)) + ((ay4 + ay5) + (ay6 + ay7))
             + ALPHA * __bfloat162float(xv.y);
    ushort2 o = make_ushort2(f2bf(ox), f2bf(oy));
    ((ushort2*)(xxbf + (size_t)wave * H))[lane] = o;
}

// ---- MFMA GEMM + epilogue: h += relu((1-b)*xx + b*(xx@W)); hbf = bf16(h) --
// block = 4 waves, 64 rows; wave = 16 rows x 128 cols (8 16x16 acc tiles).
// do_out: also emit out = h @ W_out^T + b_out (last layer; fp32 hv in regs).
__global__ __launch_bounds__(256) void k_gemm(const unsigned short* __restrict__ xxbf,
                       float* __restrict__ h, const unsigned short* __restrict__ Wtbf,
                       unsigned short* __restrict__ hbf, float beta,
                       const float* __restrict__ Wout, const float* __restrict__ bout,
                       float* __restrict__ out, int do_out) {
    int t = threadIdx.x;
    int wv = t >> 6, lane = t & 63;
    int quad = lane >> 4, l16 = lane & 15;
    int rbase = blockIdx.x * 64 + wv * 16;

    f32x4 acc[8];
    #pragma unroll
    for (int j = 0; j < 8; j++) acc[j] = (f32x4){0.f, 0.f, 0.f, 0.f};

    #pragma unroll
    for (int k0 = 0; k0 < 4; k0++) {
        bf16x8 av = *(const bf16x8*)(xxbf + (size_t)(rbase + l16) * H + k0 * 32 + quad * 8);
        #pragma unroll
        for (int j = 0; j < 8; j++) {
            bf16x8 bv = *(const bf16x8*)(Wtbf + (size_t)(j * 16 + l16) * H + k0 * 32 + quad * 8);
            acc[j] = __builtin_amdgcn_mfma_f32_16x16x32_bf16(av, bv, acc[j], 0, 0, 0);
        }
    }

    float omb = 1.f - beta;
    float po[4][3];
    #pragma unroll
    for (int r = 0; r < 4; r++) { po[r][0] = 0.f; po[r][1] = 0.f; po[r][2] = 0.f; }

    #pragma unroll
    for (int j = 0; j < 8; j++) {
        int col = j * 16 + l16;
        float w0 = 0.f, w1 = 0.f, w2 = 0.f;
        if (do_out) { w0 = Wout[col]; w1 = Wout[H + col]; w2 = Wout[2 * H + col]; }
        #pragma unroll
        for (int r = 0; r < 4; r++) {
            int row = rbase + quad * 4 + r;        // C/D: row = quad*4 + reg
            size_t idx = (size_t)row * H + col;
            float sk = bf2f(xxbf[idx]);            // skip term (bf16)
            float o = omb * sk + beta * acc[j][r];
            float hv = h[idx] + fmaxf(o, 0.f);
            h[idx] = hv;
            hbf[idx] = f2bf(hv);
            po[r][0] += hv * w0; po[r][1] += hv * w1; po[r][2] += hv * w2;
        }
    }

    if (do_out) {
        // reduce across the 16 lanes of each quad (xor strides stay in-quad)
        #pragma unroll
        for (int off = 1; off < 16; off <<= 1) {
            #pragma unroll
            for (int r = 0; r < 4; r++) {
                po[r][0] += __shfl_xor(po[r][0], off);
                po[r][1] += __shfl_xor(po[r][1], off);
                po[r][2] += __shfl_xor(po[r][2], off);
            }
        }
        if (l16 == 0) {
            #pragma unroll
            for (int r = 0; r < 4; r++) {
                int row = rbase + quad * 4 + r;
                out[(size_t)row * 3 + 0] = po[r][0] + bout[0];
                out[(size_t)row * 3 + 1] = po[r][1] + bout[1];
                out[(size_t)row * 3 + 2] = po[r][2] + bout[2];
            }
        }
    }
}

extern "C" void kernel_launch(void* const* d_in, const int* in_sizes, int n_in,
                              void* d_out, int out_size, void* d_ws, size_t ws_size,
                              hipStream_t stream) {
    const float* x     = (const float*)d_in[0];
    const int*   erow  = (const int*)  d_in[1];
    const int*   ecol  = (const int*)  d_in[2];
    const float* ew    = (const float*)d_in[3];
    const float* Win   = (const float*)d_in[4];
    const float* bin   = (const float*)d_in[5];
    const float* Wout  = (const float*)d_in[6];
    const float* bout  = (const float*)d_in[7];
    const float* Wconv = (const float*)d_in[8];
    float* out = (float*)d_out;

    char* ws = (char*)d_ws;
    const size_t NHf = (size_t)N_NODES * H * sizeof(float);           // 20,480,000
    const size_t NHb = (size_t)N_NODES * H * sizeof(unsigned short);  // 10,240,000
    float*          h     = (float*)(ws);
    unsigned short* xxbf  = (unsigned short*)(ws + NHf);
    unsigned short* x0bf  = (unsigned short*)(ws + NHf + NHb);
    unsigned short* hbf   = (unsigned short*)(ws + NHf + 2 * NHb);
    char* p = ws + NHf + 3 * NHb;
    unsigned short* Wtbf  = (unsigned short*)p;  p += 8 * H * H * 2;  // 262,144
    int*  counts  = (int*) p;  p += 160256;
    int*  row_ptr = (int*) p;  p += 160256;
    int*  cursor  = (int*) p;  p += 160256;
    int*  partial = (int*) p;  p += 1024;
    unsigned int* ep4 = (unsigned int*)p;        // NE * 4 bytes

    // CSR build (inputs restored pristine before every call)
    hipMemsetAsync(counts, 0, (size_t)N_NODES * 4, stream);
    k_hist   <<<NE / 256, 256, 0, stream>>>(erow, counts);
    k_scan1  <<<SCAN_B,   256, 0, stream>>>(counts, row_ptr, partial);
    k_scan2  <<<1,        256, 0, stream>>>(partial);
    k_scan3  <<<SCAN_B,   256, 0, stream>>>(partial, row_ptr, cursor);
    k_scatter<<<NE / 256, 256, 0, stream>>>(erow, ecol, ew, cursor, ep4);

    // weight prep + input projection
    k_wprep<<<8 * H * H / 256, 256, 0, stream>>>(Wconv, Wtbf);
    k_xin  <<<N_NODES / 16,    256, 0, stream>>>(x, Win, bin, h, x0bf, hbf);

    // layers: spmm -> xxbf (bf16); gemm: h += relu(...), refresh hbf;
    // last layer's gemm also emits the output projection.
    for (int l = 0; l < NLAYERS; l++) {
        float beta = logf(THETA / (float)(l + 1) + 1.0f);
        k_spmm<<<N_NODES / 4,  256, 0, stream>>>(row_ptr, ep4, hbf, x0bf, xxbf);
        k_gemm<<<N_NODES / 64, 256, 0, stream>>>(xxbf, h, Wtbf + (size_t)l * H * H,
                                                 hbf, beta, Wout, bout, out,
                                                 (l == NLAYERS - 1) ? 1 : 0);
    }
}